// Round 1
// baseline (897.341 us; speedup 1.0000x reference)
//
#include <hip/hip_runtime.h>
#include <hip/hip_bf16.h>
#include <stdint.h>

#define MARGIN_C 0.5f
#define POS_MARGIN_C 0.05f
#define EPS_C 1e-6f

typedef __bf16 bf16x8 __attribute__((ext_vector_type(8)));
typedef float f32x4 __attribute__((ext_vector_type(4)));

static __device__ __forceinline__ void gload_lds16(const void* g, void* lds) {
    __builtin_amdgcn_global_load_lds(
        (const __attribute__((address_space(1))) char*)g,
        (__attribute__((address_space(3))) char*)lds,
        16, 0, 0);
}

// ---------------------------------------------------------------------------
// f32 -> bf16 conversion (vectorized: 8 floats -> 16B bf16 per iter)
// ---------------------------------------------------------------------------
__global__ void cvt_f32_to_bf16(const float* __restrict__ in,
                                short* __restrict__ out, int n) {
    int idx = blockIdx.x * blockDim.x + threadIdx.x;
    int stride = gridDim.x * blockDim.x;
    int n8 = n >> 3;
    for (int i = idx; i < n8; i += stride) {
        float4 a = ((const float4*)in)[2 * i];
        float4 b = ((const float4*)in)[2 * i + 1];
        bf16x8 o;
        o[0] = (__bf16)a.x; o[1] = (__bf16)a.y; o[2] = (__bf16)a.z; o[3] = (__bf16)a.w;
        o[4] = (__bf16)b.x; o[5] = (__bf16)b.y; o[6] = (__bf16)b.z; o[7] = (__bf16)b.w;
        ((bf16x8*)out)[i] = o;
    }
}

// ---------------------------------------------------------------------------
// Main fused kernel: 128x128 tile, 4 waves (2x2 of 64x64), BK=64,
// global_load_lds staging with st-swizzle, fused mask+reduce epilogue.
// ---------------------------------------------------------------------------
__global__ __launch_bounds__(256) void sim_loss_mfma(
    const short* __restrict__ Abf, const short* __restrict__ Bbf,
    const int* __restrict__ L1, const int* __restrict__ L2,
    float* __restrict__ accum, int N, int M, int D) {
    __shared__ __align__(16) short smA[128 * 64];
    __shared__ __align__(16) short smB[128 * 64];
    __shared__ int sl1[128];
    __shared__ int sl2[128];

    const int tid = threadIdx.x;
    const int lane = tid & 63;
    const int w = tid >> 6;              // wave 0..3
    const int wR = w >> 1, wC = w & 1;   // 2x2 wave grid

    const int nby = M >> 7;
    const int nwg = (N >> 7) * nby;
    int wg = blockIdx.x;
    if ((nwg & 7) == 0) wg = (wg & 7) * (nwg >> 3) + (wg >> 3);  // XCD swizzle
    const int bi = wg / nby, bj = wg % nby;
    const int i0 = bi << 7, j0 = bj << 7;

    if (tid < 128) sl1[tid] = L1[i0 + tid];
    else           sl2[tid - 128] = L2[j0 + tid - 128];

    f32x4 acc[4][4] = {};

    const int kTiles = D >> 6;
    for (int kt = 0; kt < kTiles; ++kt) {
        const int k0 = kt << 6;
        // stage A and B tiles: 1024 16B-chunks each, 4 rounds of 256 threads
#pragma unroll
        for (int s = 0; s < 4; ++s) {
            int chunk = s * 256 + tid;
            int row = chunk >> 3, c = chunk & 7;
            int cs = c ^ (row & 7);  // inverse-swizzled global source (rule 21)
            const short* gA = Abf + (size_t)(i0 + row) * D + k0 + cs * 8;
            const short* gB = Bbf + (size_t)(j0 + row) * D + k0 + cs * 8;
            int ldsoff = (s * 256 + (tid & ~63)) * 16;  // wave-uniform byte base
            gload_lds16(gA, (char*)smA + ldsoff);
            gload_lds16(gB, (char*)smB + ldsoff);
        }
        __syncthreads();
#pragma unroll
        for (int ks = 0; ks < 2; ++ks) {
            const int r = lane & 15;
            const int cchunk = (ks << 2) + (lane >> 4);  // 16B chunk idx 0..7
            bf16x8 a[4], b[4];
#pragma unroll
            for (int m = 0; m < 4; ++m) {
                int row = wR * 64 + m * 16 + r;
                int sw = cchunk ^ (row & 7);
                a[m] = *(const bf16x8*)((const char*)smA + row * 128 + sw * 16);
            }
#pragma unroll
            for (int n = 0; n < 4; ++n) {
                int row = wC * 64 + n * 16 + r;
                int sw = cchunk ^ (row & 7);
                b[n] = *(const bf16x8*)((const char*)smB + row * 128 + sw * 16);
            }
#pragma unroll
            for (int m = 0; m < 4; ++m)
#pragma unroll
                for (int n = 0; n < 4; ++n)
                    acc[m][n] = __builtin_amdgcn_mfma_f32_16x16x32_bf16(
                        a[m], b[n], acc[m][n], 0, 0, 0);
        }
        __syncthreads();
    }

    // Fused epilogue: C/D layout col=lane&15, row=(lane>>4)*4+v
    float psum = 0.f, nsum = 0.f, pcnt = 0.f, ncnt = 0.f;
    const int colc = lane & 15;
    const int rquad = (lane >> 4) * 4;
#pragma unroll
    for (int m = 0; m < 4; ++m) {
#pragma unroll
        for (int n = 0; n < 4; ++n) {
            int lj = sl2[wC * 64 + n * 16 + colc];
#pragma unroll
            for (int v = 0; v < 4; ++v) {
                int li = sl1[wR * 64 + m * 16 + rquad + v];
                float s = acc[m][n][v];
                if (li > 0) {
                    if (li == lj) {
                        if (s < 1.0f - EPS_C - POS_MARGIN_C) { psum += 1.0f - s; pcnt += 1.f; }
                    } else {
                        if (s > MARGIN_C) { nsum += s; ncnt += 1.f; }
                    }
                }
            }
        }
    }
#pragma unroll
    for (int off = 32; off; off >>= 1) {
        psum += __shfl_down(psum, off);
        nsum += __shfl_down(nsum, off);
        pcnt += __shfl_down(pcnt, off);
        ncnt += __shfl_down(ncnt, off);
    }
    if (lane == 0) {
        atomicAdd(&accum[0], psum);
        atomicAdd(&accum[1], nsum);
        atomicAdd(&accum[2], pcnt);
        atomicAdd(&accum[3], ncnt);
    }
}

// ---------------------------------------------------------------------------
// Fallback (ws too small): f32 LDS-tiled 64x64, fused epilogue
// ---------------------------------------------------------------------------
__global__ __launch_bounds__(256) void sim_loss_f32(
    const float* __restrict__ X1, const float* __restrict__ X2,
    const int* __restrict__ L1, const int* __restrict__ L2,
    float* __restrict__ accum, int N, int M, int D) {
    __shared__ float sA[64][33];
    __shared__ float sB[64][33];
    __shared__ int sl1[64], sl2[64];
    const int tid = threadIdx.x;
    const int nby = M >> 6;
    const int bi = blockIdx.x / nby, bj = blockIdx.x % nby;
    const int i0 = bi << 6, j0 = bj << 6;
    if (tid < 64) sl1[tid] = L1[i0 + tid];
    else if (tid < 128) sl2[tid - 64] = L2[j0 + tid - 64];
    const int tx = tid & 15, ty = tid >> 4;
    float acc[4][4] = {};
    for (int k0 = 0; k0 < D; k0 += 32) {
#pragma unroll
        for (int s = 0; s < 8; ++s) {
            int e = s * 256 + tid;
            int row = e >> 5, col = e & 31;
            sA[row][col] = X1[(size_t)(i0 + row) * D + k0 + col];
            sB[row][col] = X2[(size_t)(j0 + row) * D + k0 + col];
        }
        __syncthreads();
#pragma unroll 8
        for (int kk = 0; kk < 32; ++kk) {
            float av[4], bv[4];
#pragma unroll
            for (int p = 0; p < 4; ++p) { av[p] = sA[ty * 4 + p][kk]; bv[p] = sB[tx * 4 + p][kk]; }
#pragma unroll
            for (int p = 0; p < 4; ++p)
#pragma unroll
                for (int q = 0; q < 4; ++q) acc[p][q] += av[p] * bv[q];
        }
        __syncthreads();
    }
    float psum = 0.f, nsum = 0.f, pcnt = 0.f, ncnt = 0.f;
#pragma unroll
    for (int p = 0; p < 4; ++p) {
        int li = sl1[ty * 4 + p];
#pragma unroll
        for (int q = 0; q < 4; ++q) {
            int lj = sl2[tx * 4 + q];
            float s = acc[p][q];
            if (li > 0) {
                if (li == lj) {
                    if (s < 1.0f - EPS_C - POS_MARGIN_C) { psum += 1.0f - s; pcnt += 1.f; }
                } else {
                    if (s > MARGIN_C) { nsum += s; ncnt += 1.f; }
                }
            }
        }
    }
#pragma unroll
    for (int off = 32; off; off >>= 1) {
        psum += __shfl_down(psum, off);
        nsum += __shfl_down(nsum, off);
        pcnt += __shfl_down(pcnt, off);
        ncnt += __shfl_down(ncnt, off);
    }
    if ((tid & 63) == 0) {
        atomicAdd(&accum[0], psum);
        atomicAdd(&accum[1], nsum);
        atomicAdd(&accum[2], pcnt);
        atomicAdd(&accum[3], ncnt);
    }
}

// ---------------------------------------------------------------------------
// Finalize: n = sum(labels1 > 0); write 3 outputs
// ---------------------------------------------------------------------------
__global__ void finalize_kernel(const int* __restrict__ L1, int N,
                                const float* __restrict__ accum,
                                float* __restrict__ out) {
    __shared__ float red[256];
    const int tid = threadIdx.x;
    int cnt = 0;
    for (int i = tid; i < N; i += 256) cnt += (L1[i] > 0) ? 1 : 0;
    red[tid] = (float)cnt;
    __syncthreads();
    for (int st = 128; st; st >>= 1) {
        if (tid < st) red[tid] += red[tid + st];
        __syncthreads();
    }
    if (tid == 0) {
        float n = red[0];
        out[0] = (accum[0] + accum[1]) / n;                 // loss
        out[1] = accum[3] / n;                              // avg_neg
        out[2] = rintf(100.f * accum[2] / n) * 0.01f;       // avg_pos (round-half-even)
    }
}

extern "C" void kernel_launch(void* const* d_in, const int* in_sizes, int n_in,
                              void* d_out, int out_size, void* d_ws, size_t ws_size,
                              hipStream_t stream) {
    const float* x1 = (const float*)d_in[0];
    const int* l1 = (const int*)d_in[1];
    const float* x2 = (const float*)d_in[2];
    const int* l2 = (const int*)d_in[3];
    const int N = in_sizes[1];
    const int M = in_sizes[3];
    const int D = in_sizes[0] / N;
    float* out = (float*)d_out;
    float* accum = (float*)d_ws;

    hipMemsetAsync(accum, 0, 4 * sizeof(float), stream);

    const size_t offA = 256;
    const size_t offB = offA + (size_t)N * D * 2;
    const size_t need = offB + (size_t)M * D * 2;
    const bool fast = (ws_size >= need) && ((N & 127) == 0) && ((M & 127) == 0) &&
                      ((D & 63) == 0);

    if (fast) {
        short* Abf = (short*)((char*)d_ws + offA);
        short* Bbf = (short*)((char*)d_ws + offB);
        cvt_f32_to_bf16<<<2048, 256, 0, stream>>>(x1, Abf, N * D);
        cvt_f32_to_bf16<<<2048, 256, 0, stream>>>(x2, Bbf, M * D);
        const int nwg = (N >> 7) * (M >> 7);
        sim_loss_mfma<<<nwg, 256, 0, stream>>>(Abf, Bbf, l1, l2, accum, N, M, D);
    } else {
        const int nwg = (N >> 6) * (M >> 6);
        sim_loss_f32<<<nwg, 256, 0, stream>>>(x1, x2, l1, l2, accum, N, M, D);
    }
    finalize_kernel<<<1, 256, 0, stream>>>(l1, N, accum, out);
}

// Round 2
// 153.851 us; speedup vs baseline: 5.8325x; 5.8325x over previous
//
#include <hip/hip_runtime.h>
#include <hip/hip_bf16.h>
#include <stdint.h>

#define MARGIN_C 0.5f
#define POS_MARGIN_C 0.05f
#define EPS_C 1e-6f

typedef __bf16 bf16x8 __attribute__((ext_vector_type(8)));
typedef float f32x4 __attribute__((ext_vector_type(4)));

static __device__ __forceinline__ void gload_lds16(const void* g, void* lds) {
    __builtin_amdgcn_global_load_lds(
        (const __attribute__((address_space(1))) char*)g,
        (__attribute__((address_space(3))) char*)lds,
        16, 0, 0);
}

// ---------------------------------------------------------------------------
// f32 -> bf16 conversion (vectorized: 8 floats -> 16B bf16 per iter)
// ---------------------------------------------------------------------------
__global__ void cvt_f32_to_bf16(const float* __restrict__ in,
                                short* __restrict__ out, int n) {
    int idx = blockIdx.x * blockDim.x + threadIdx.x;
    int stride = gridDim.x * blockDim.x;
    int n8 = n >> 3;
    for (int i = idx; i < n8; i += stride) {
        float4 a = ((const float4*)in)[2 * i];
        float4 b = ((const float4*)in)[2 * i + 1];
        bf16x8 o;
        o[0] = (__bf16)a.x; o[1] = (__bf16)a.y; o[2] = (__bf16)a.z; o[3] = (__bf16)a.w;
        o[4] = (__bf16)b.x; o[5] = (__bf16)b.y; o[6] = (__bf16)b.z; o[7] = (__bf16)b.w;
        ((bf16x8*)out)[i] = o;
    }
}

// ---------------------------------------------------------------------------
// Main fused kernel: 128x128 tile, 4 waves (2x2 of 64x64), BK=64,
// global_load_lds staging with st-swizzle, fused mask+reduce epilogue.
// Epilogue: block-level LDS reduce -> ONE non-atomic float4 store per block.
// ---------------------------------------------------------------------------
__global__ __launch_bounds__(256) void sim_loss_mfma(
    const short* __restrict__ Abf, const short* __restrict__ Bbf,
    const int* __restrict__ L1, const int* __restrict__ L2,
    float* __restrict__ partials, int N, int M, int D) {
    __shared__ __align__(16) short smA[128 * 64];
    __shared__ __align__(16) short smB[128 * 64];
    __shared__ int sl1[128];
    __shared__ int sl2[128];
    __shared__ float red4[4][4];

    const int tid = threadIdx.x;
    const int lane = tid & 63;
    const int w = tid >> 6;              // wave 0..3
    const int wR = w >> 1, wC = w & 1;   // 2x2 wave grid

    const int nby = M >> 7;
    const int nwg = (N >> 7) * nby;
    int wg = blockIdx.x;
    if ((nwg & 7) == 0) wg = (wg & 7) * (nwg >> 3) + (wg >> 3);  // XCD swizzle
    const int bi = wg / nby, bj = wg % nby;
    const int i0 = bi << 7, j0 = bj << 7;

    if (tid < 128) sl1[tid] = L1[i0 + tid];
    else           sl2[tid - 128] = L2[j0 + tid - 128];

    f32x4 acc[4][4] = {};

    const int kTiles = D >> 6;
    for (int kt = 0; kt < kTiles; ++kt) {
        const int k0 = kt << 6;
        // stage A and B tiles: 1024 16B-chunks each, 4 rounds of 256 threads
#pragma unroll
        for (int s = 0; s < 4; ++s) {
            int chunk = s * 256 + tid;
            int row = chunk >> 3, c = chunk & 7;
            int cs = c ^ (row & 7);  // inverse-swizzled global source (rule 21)
            const short* gA = Abf + (size_t)(i0 + row) * D + k0 + cs * 8;
            const short* gB = Bbf + (size_t)(j0 + row) * D + k0 + cs * 8;
            int ldsoff = (s * 256 + (tid & ~63)) * 16;  // wave-uniform byte base
            gload_lds16(gA, (char*)smA + ldsoff);
            gload_lds16(gB, (char*)smB + ldsoff);
        }
        __syncthreads();
#pragma unroll
        for (int ks = 0; ks < 2; ++ks) {
            const int r = lane & 15;
            const int cchunk = (ks << 2) + (lane >> 4);  // 16B chunk idx 0..7
            bf16x8 a[4], b[4];
#pragma unroll
            for (int m = 0; m < 4; ++m) {
                int row = wR * 64 + m * 16 + r;
                int sw = cchunk ^ (row & 7);
                a[m] = *(const bf16x8*)((const char*)smA + row * 128 + sw * 16);
            }
#pragma unroll
            for (int n = 0; n < 4; ++n) {
                int row = wC * 64 + n * 16 + r;
                int sw = cchunk ^ (row & 7);
                b[n] = *(const bf16x8*)((const char*)smB + row * 128 + sw * 16);
            }
#pragma unroll
            for (int m = 0; m < 4; ++m)
#pragma unroll
                for (int n = 0; n < 4; ++n)
                    acc[m][n] = __builtin_amdgcn_mfma_f32_16x16x32_bf16(
                        a[m], b[n], acc[m][n], 0, 0, 0);
        }
        __syncthreads();
    }

    // Fused epilogue: C/D layout col=lane&15, row=(lane>>4)*4+v
    float psum = 0.f, nsum = 0.f, pcnt = 0.f, ncnt = 0.f;
    const int colc = lane & 15;
    const int rquad = (lane >> 4) * 4;
#pragma unroll
    for (int m = 0; m < 4; ++m) {
#pragma unroll
        for (int n = 0; n < 4; ++n) {
            int lj = sl2[wC * 64 + n * 16 + colc];
#pragma unroll
            for (int v = 0; v < 4; ++v) {
                int li = sl1[wR * 64 + m * 16 + rquad + v];
                float s = acc[m][n][v];
                if (li > 0) {
                    if (li == lj) {
                        if (s < 1.0f - EPS_C - POS_MARGIN_C) { psum += 1.0f - s; pcnt += 1.f; }
                    } else {
                        if (s > MARGIN_C) { nsum += s; ncnt += 1.f; }
                    }
                }
            }
        }
    }
#pragma unroll
    for (int off = 32; off; off >>= 1) {
        psum += __shfl_down(psum, off);
        nsum += __shfl_down(nsum, off);
        pcnt += __shfl_down(pcnt, off);
        ncnt += __shfl_down(ncnt, off);
    }
    if (lane == 0) {
        red4[w][0] = psum; red4[w][1] = nsum; red4[w][2] = pcnt; red4[w][3] = ncnt;
    }
    __syncthreads();
    if (tid == 0) {
        float4 o;
        o.x = red4[0][0] + red4[1][0] + red4[2][0] + red4[3][0];
        o.y = red4[0][1] + red4[1][1] + red4[2][1] + red4[3][1];
        o.z = red4[0][2] + red4[1][2] + red4[2][2] + red4[3][2];
        o.w = red4[0][3] + red4[1][3] + red4[2][3] + red4[3][3];
        ((float4*)partials)[blockIdx.x] = o;  // non-atomic, deterministic
    }
}

// ---------------------------------------------------------------------------
// Fallback (ws too small): f32 LDS-tiled 64x64, fused epilogue
// ---------------------------------------------------------------------------
__global__ __launch_bounds__(256) void sim_loss_f32(
    const float* __restrict__ X1, const float* __restrict__ X2,
    const int* __restrict__ L1, const int* __restrict__ L2,
    float* __restrict__ partials, int N, int M, int D) {
    __shared__ float sA[64][33];
    __shared__ float sB[64][33];
    __shared__ int sl1[64], sl2[64];
    __shared__ float red4[4][4];
    const int tid = threadIdx.x;
    const int nby = M >> 6;
    const int bi = blockIdx.x / nby, bj = blockIdx.x % nby;
    const int i0 = bi << 6, j0 = bj << 6;
    if (tid < 64) sl1[tid] = L1[i0 + tid];
    else if (tid < 128) sl2[tid - 64] = L2[j0 + tid - 64];
    const int tx = tid & 15, ty = tid >> 4;
    float acc[4][4] = {};
    for (int k0 = 0; k0 < D; k0 += 32) {
#pragma unroll
        for (int s = 0; s < 8; ++s) {
            int e = s * 256 + tid;
            int row = e >> 5, col = e & 31;
            sA[row][col] = X1[(size_t)(i0 + row) * D + k0 + col];
            sB[row][col] = X2[(size_t)(j0 + row) * D + k0 + col];
        }
        __syncthreads();
#pragma unroll 8
        for (int kk = 0; kk < 32; ++kk) {
            float av[4], bv[4];
#pragma unroll
            for (int p = 0; p < 4; ++p) { av[p] = sA[ty * 4 + p][kk]; bv[p] = sB[tx * 4 + p][kk]; }
#pragma unroll
            for (int p = 0; p < 4; ++p)
#pragma unroll
                for (int q = 0; q < 4; ++q) acc[p][q] += av[p] * bv[q];
        }
        __syncthreads();
    }
    float psum = 0.f, nsum = 0.f, pcnt = 0.f, ncnt = 0.f;
#pragma unroll
    for (int p = 0; p < 4; ++p) {
        int li = sl1[ty * 4 + p];
#pragma unroll
        for (int q = 0; q < 4; ++q) {
            int lj = sl2[tx * 4 + q];
            float s = acc[p][q];
            if (li > 0) {
                if (li == lj) {
                    if (s < 1.0f - EPS_C - POS_MARGIN_C) { psum += 1.0f - s; pcnt += 1.f; }
                } else {
                    if (s > MARGIN_C) { nsum += s; ncnt += 1.f; }
                }
            }
        }
    }
#pragma unroll
    for (int off = 32; off; off >>= 1) {
        psum += __shfl_down(psum, off);
        nsum += __shfl_down(nsum, off);
        pcnt += __shfl_down(pcnt, off);
        ncnt += __shfl_down(ncnt, off);
    }
    const int w = tid >> 6;
    if ((tid & 63) == 0) {
        red4[w][0] = psum; red4[w][1] = nsum; red4[w][2] = pcnt; red4[w][3] = ncnt;
    }
    __syncthreads();
    if (tid == 0) {
        float4 o;
        o.x = red4[0][0] + red4[1][0] + red4[2][0] + red4[3][0];
        o.y = red4[0][1] + red4[1][1] + red4[2][1] + red4[3][1];
        o.z = red4[0][2] + red4[1][2] + red4[2][2] + red4[3][2];
        o.w = red4[0][3] + red4[1][3] + red4[2][3] + red4[3][3];
        ((float4*)partials)[blockIdx.x] = o;
    }
}

// ---------------------------------------------------------------------------
// Finalize: deterministic reduce of per-block partials; n = sum(labels1 > 0)
// ---------------------------------------------------------------------------
__global__ void finalize_kernel(const int* __restrict__ L1, int N,
                                const float* __restrict__ partials, int nblocks,
                                float* __restrict__ out) {
    __shared__ float red[256][4];
    __shared__ float redn[256];
    const int tid = threadIdx.x;
    float s0 = 0.f, s1 = 0.f, s2 = 0.f, s3 = 0.f;
    for (int i = tid; i < nblocks; i += 256) {
        float4 p = ((const float4*)partials)[i];
        s0 += p.x; s1 += p.y; s2 += p.z; s3 += p.w;
    }
    int cnt = 0;
    for (int i = tid; i < N; i += 256) cnt += (L1[i] > 0) ? 1 : 0;
    red[tid][0] = s0; red[tid][1] = s1; red[tid][2] = s2; red[tid][3] = s3;
    redn[tid] = (float)cnt;
    __syncthreads();
    for (int st = 128; st; st >>= 1) {
        if (tid < st) {
            red[tid][0] += red[tid + st][0];
            red[tid][1] += red[tid + st][1];
            red[tid][2] += red[tid + st][2];
            red[tid][3] += red[tid + st][3];
            redn[tid] += redn[tid + st];
        }
        __syncthreads();
    }
    if (tid == 0) {
        float n = redn[0];
        float psum = red[0][0], nsum = red[0][1], pcnt = red[0][2], ncnt = red[0][3];
        out[0] = (psum + nsum) / n;                  // loss
        out[1] = ncnt / n;                           // avg_neg
        out[2] = rintf(100.f * pcnt / n) * 0.01f;    // avg_pos (round-half-even)
    }
}

extern "C" void kernel_launch(void* const* d_in, const int* in_sizes, int n_in,
                              void* d_out, int out_size, void* d_ws, size_t ws_size,
                              hipStream_t stream) {
    const float* x1 = (const float*)d_in[0];
    const int* l1 = (const int*)d_in[1];
    const float* x2 = (const float*)d_in[2];
    const int* l2 = (const int*)d_in[3];
    const int N = in_sizes[1];
    const int M = in_sizes[3];
    const int D = in_sizes[0] / N;
    float* out = (float*)d_out;

    // ws layout (fast path): [partials: 64 KB][Abf: N*D*2][Bbf: M*D*2]
    const size_t offPart = 0;
    const size_t offA = 65536;
    const size_t offB = offA + (size_t)N * D * 2;
    const size_t need = offB + (size_t)M * D * 2;
    const int nwgFast = ((N >> 7) * (M >> 7));
    const bool fast = (ws_size >= need) && ((N & 127) == 0) && ((M & 127) == 0) &&
                      ((D & 63) == 0) && (nwgFast * 16 <= 65536);

    if (fast) {
        float* partials = (float*)((char*)d_ws + offPart);
        short* Abf = (short*)((char*)d_ws + offA);
        short* Bbf = (short*)((char*)d_ws + offB);
        cvt_f32_to_bf16<<<2048, 256, 0, stream>>>(x1, Abf, N * D);
        cvt_f32_to_bf16<<<2048, 256, 0, stream>>>(x2, Bbf, M * D);
        sim_loss_mfma<<<nwgFast, 256, 0, stream>>>(Abf, Bbf, l1, l2, partials, N, M, D);
        finalize_kernel<<<1, 256, 0, stream>>>(l1, N, partials, nwgFast, out);
    } else {
        float* partials = (float*)d_ws;
        const int nwg = (N >> 6) * (M >> 6);
        sim_loss_f32<<<nwg, 256, 0, stream>>>(x1, x2, l1, l2, partials, N, M, D);
        finalize_kernel<<<1, 256, 0, stream>>>(l1, N, partials, nwg, out);
    }
}

// Round 3
// 114.894 us; speedup vs baseline: 7.8102x; 1.3391x over previous
//
#include <hip/hip_runtime.h>
#include <hip/hip_bf16.h>
#include <stdint.h>

#define MARGIN_C 0.5f
#define POS_MARGIN_C 0.05f
#define EPS_C 1e-6f

typedef float f32x4 __attribute__((ext_vector_type(4)));
typedef int i32x4v __attribute__((ext_vector_type(4)));
typedef int i32x8v __attribute__((ext_vector_type(8)));

static __device__ __forceinline__ void gload_lds16(const void* g, void* lds) {
    __builtin_amdgcn_global_load_lds(
        (const __attribute__((address_space(1))) char*)g,
        (__attribute__((address_space(3))) char*)lds,
        16, 0, 0);
}

// ---------------------------------------------------------------------------
// f32 -> fp8 e4m3 (OCP) conversion: 16 floats -> 16 bytes per iter
// ---------------------------------------------------------------------------
__global__ void cvt_f32_to_fp8(const float* __restrict__ in,
                               uint32_t* __restrict__ out, int n) {
    int idx = blockIdx.x * blockDim.x + threadIdx.x;
    int stride = gridDim.x * blockDim.x;
    int n16 = n >> 4;
    for (int i = idx; i < n16; i += stride) {
        float4 a = ((const float4*)in)[4 * i];
        float4 b = ((const float4*)in)[4 * i + 1];
        float4 c = ((const float4*)in)[4 * i + 2];
        float4 d = ((const float4*)in)[4 * i + 3];
        uint32_t w0 = 0, w1 = 0, w2 = 0, w3 = 0;
        w0 = __builtin_amdgcn_cvt_pk_fp8_f32(a.x, a.y, w0, false);
        w0 = __builtin_amdgcn_cvt_pk_fp8_f32(a.z, a.w, w0, true);
        w1 = __builtin_amdgcn_cvt_pk_fp8_f32(b.x, b.y, w1, false);
        w1 = __builtin_amdgcn_cvt_pk_fp8_f32(b.z, b.w, w1, true);
        w2 = __builtin_amdgcn_cvt_pk_fp8_f32(c.x, c.y, w2, false);
        w2 = __builtin_amdgcn_cvt_pk_fp8_f32(c.z, c.w, w2, true);
        w3 = __builtin_amdgcn_cvt_pk_fp8_f32(d.x, d.y, w3, false);
        w3 = __builtin_amdgcn_cvt_pk_fp8_f32(d.z, d.w, w3, true);
        uint4 o; o.x = w0; o.y = w1; o.z = w2; o.w = w3;
        ((uint4*)out)[i] = o;
    }
}

// ---------------------------------------------------------------------------
// Main fused kernel: 128x128 tile, 4 waves (2x2 of 64x64), BK=128 fp8,
// MX-scaled MFMA 16x16x128 (scales = 1.0), global_load_lds staging with
// chunk-XOR swizzle, fused mask+reduce epilogue, one float4 store per block.
// ---------------------------------------------------------------------------
__global__ __launch_bounds__(256) void sim_loss_mfma(
    const char* __restrict__ Af8, const char* __restrict__ Bf8,
    const int* __restrict__ L1, const int* __restrict__ L2,
    float* __restrict__ partials, int N, int M, int D) {
    __shared__ __align__(16) char smA[128 * 128];   // 16 KB
    __shared__ __align__(16) char smB[128 * 128];   // 16 KB
    __shared__ int sl1[128];
    __shared__ int sl2[128];
    __shared__ float red4[4][4];

    const int tid = threadIdx.x;
    const int lane = tid & 63;
    const int w = tid >> 6;              // wave 0..3
    const int wR = w >> 1, wC = w & 1;   // 2x2 wave grid

    const int nby = M >> 7;
    const int nwg = (N >> 7) * nby;
    int wg = blockIdx.x;
    if ((nwg & 7) == 0) wg = (wg & 7) * (nwg >> 3) + (wg >> 3);  // XCD swizzle
    const int bi = wg / nby, bj = wg % nby;
    const int i0 = bi << 7, j0 = bj << 7;

    if (tid < 128) sl1[tid] = L1[i0 + tid];
    else           sl2[tid - 128] = L2[j0 + tid - 128];

    f32x4 acc[4][4] = {};

    const int kTiles = D >> 7;          // BK = 128 fp8 elements = 128 bytes/row
    for (int kt = 0; kt < kTiles; ++kt) {
        const int k0 = kt << 7;
        // stage A and B tiles: 1024 16B-chunks each, 4 rounds of 256 threads
#pragma unroll
        for (int s = 0; s < 4; ++s) {
            int chunk = s * 256 + tid;
            int row = chunk >> 3, c = chunk & 7;
            int cs = c ^ (row & 7);  // inverse-swizzled global source (rule 21)
            const char* gA = Af8 + (size_t)(i0 + row) * D + k0 + cs * 16;
            const char* gB = Bf8 + (size_t)(j0 + row) * D + k0 + cs * 16;
            int ldsoff = (s * 256 + (tid & ~63)) * 16;  // wave-uniform byte base
            gload_lds16(gA, smA + ldsoff);
            gload_lds16(gB, smB + ldsoff);
        }
        __syncthreads();

        const int r = lane & 15;
        const int q = lane >> 4;         // k-block: bytes [q*32, q*32+32)
        i32x8v a[4];
#pragma unroll
        for (int m = 0; m < 4; ++m) {
            int row = wR * 64 + m * 16 + r;
            int sw = row & 7;
            i32x4v lo = *(const i32x4v*)(smA + row * 128 + ((2 * q) ^ sw) * 16);
            i32x4v hi = *(const i32x4v*)(smA + row * 128 + ((2 * q + 1) ^ sw) * 16);
            a[m][0] = lo[0]; a[m][1] = lo[1]; a[m][2] = lo[2]; a[m][3] = lo[3];
            a[m][4] = hi[0]; a[m][5] = hi[1]; a[m][6] = hi[2]; a[m][7] = hi[3];
        }
#pragma unroll
        for (int n = 0; n < 4; ++n) {
            int row = wC * 64 + n * 16 + r;
            int sw = row & 7;
            i32x4v lo = *(const i32x4v*)(smB + row * 128 + ((2 * q) ^ sw) * 16);
            i32x4v hi = *(const i32x4v*)(smB + row * 128 + ((2 * q + 1) ^ sw) * 16);
            i32x8v b;
            b[0] = lo[0]; b[1] = lo[1]; b[2] = lo[2]; b[3] = lo[3];
            b[4] = hi[0]; b[5] = hi[1]; b[6] = hi[2]; b[7] = hi[3];
#pragma unroll
            for (int m = 0; m < 4; ++m)
                acc[m][n] = __builtin_amdgcn_mfma_scale_f32_16x16x128_f8f6f4(
                    a[m], b, acc[m][n], 0, 0,            // cbsz=fp8, blgp=fp8
                    0, 0x7F7F7F7F, 0, 0x7F7F7F7F);       // scales = 1.0 (e8m0 127)
        }
        __syncthreads();
    }

    // Fused epilogue: C/D layout col=lane&15, row=(lane>>4)*4+v
    float psum = 0.f, nsum = 0.f, pcnt = 0.f, ncnt = 0.f;
    const int colc = lane & 15;
    const int rquad = (lane >> 4) * 4;
#pragma unroll
    for (int m = 0; m < 4; ++m) {
#pragma unroll
        for (int n = 0; n < 4; ++n) {
            int lj = sl2[wC * 64 + n * 16 + colc];
#pragma unroll
            for (int v = 0; v < 4; ++v) {
                int li = sl1[wR * 64 + m * 16 + rquad + v];
                float s = acc[m][n][v];
                if (li > 0) {
                    if (li == lj) {
                        if (s < 1.0f - EPS_C - POS_MARGIN_C) { psum += 1.0f - s; pcnt += 1.f; }
                    } else {
                        if (s > MARGIN_C) { nsum += s; ncnt += 1.f; }
                    }
                }
            }
        }
    }
#pragma unroll
    for (int off = 32; off; off >>= 1) {
        psum += __shfl_down(psum, off);
        nsum += __shfl_down(nsum, off);
        pcnt += __shfl_down(pcnt, off);
        ncnt += __shfl_down(ncnt, off);
    }
    if (lane == 0) {
        red4[w][0] = psum; red4[w][1] = nsum; red4[w][2] = pcnt; red4[w][3] = ncnt;
    }
    __syncthreads();
    if (tid == 0) {
        float4 o;
        o.x = red4[0][0] + red4[1][0] + red4[2][0] + red4[3][0];
        o.y = red4[0][1] + red4[1][1] + red4[2][1] + red4[3][1];
        o.z = red4[0][2] + red4[1][2] + red4[2][2] + red4[3][2];
        o.w = red4[0][3] + red4[1][3] + red4[2][3] + red4[3][3];
        ((float4*)partials)[blockIdx.x] = o;  // non-atomic, deterministic
    }
}

// ---------------------------------------------------------------------------
// Fallback (ws too small / odd shapes): f32 LDS-tiled 64x64, fused epilogue
// ---------------------------------------------------------------------------
__global__ __launch_bounds__(256) void sim_loss_f32(
    const float* __restrict__ X1, const float* __restrict__ X2,
    const int* __restrict__ L1, const int* __restrict__ L2,
    float* __restrict__ partials, int N, int M, int D) {
    __shared__ float sA[64][33];
    __shared__ float sB[64][33];
    __shared__ int sl1[64], sl2[64];
    __shared__ float red4[4][4];
    const int tid = threadIdx.x;
    const int nby = M >> 6;
    const int bi = blockIdx.x / nby, bj = blockIdx.x % nby;
    const int i0 = bi << 6, j0 = bj << 6;
    if (tid < 64) sl1[tid] = L1[i0 + tid];
    else if (tid < 128) sl2[tid - 64] = L2[j0 + tid - 64];
    const int tx = tid & 15, ty = tid >> 4;
    float acc[4][4] = {};
    for (int k0 = 0; k0 < D; k0 += 32) {
#pragma unroll
        for (int s = 0; s < 8; ++s) {
            int e = s * 256 + tid;
            int row = e >> 5, col = e & 31;
            sA[row][col] = X1[(size_t)(i0 + row) * D + k0 + col];
            sB[row][col] = X2[(size_t)(j0 + row) * D + k0 + col];
        }
        __syncthreads();
#pragma unroll 8
        for (int kk = 0; kk < 32; ++kk) {
            float av[4], bv[4];
#pragma unroll
            for (int p = 0; p < 4; ++p) { av[p] = sA[ty * 4 + p][kk]; bv[p] = sB[tx * 4 + p][kk]; }
#pragma unroll
            for (int p = 0; p < 4; ++p)
#pragma unroll
                for (int q = 0; q < 4; ++q) acc[p][q] += av[p] * bv[q];
        }
        __syncthreads();
    }
    float psum = 0.f, nsum = 0.f, pcnt = 0.f, ncnt = 0.f;
#pragma unroll
    for (int p = 0; p < 4; ++p) {
        int li = sl1[ty * 4 + p];
#pragma unroll
        for (int q = 0; q < 4; ++q) {
            int lj = sl2[tx * 4 + q];
            float s = acc[p][q];
            if (li > 0) {
                if (li == lj) {
                    if (s < 1.0f - EPS_C - POS_MARGIN_C) { psum += 1.0f - s; pcnt += 1.f; }
                } else {
                    if (s > MARGIN_C) { nsum += s; ncnt += 1.f; }
                }
            }
        }
    }
#pragma unroll
    for (int off = 32; off; off >>= 1) {
        psum += __shfl_down(psum, off);
        nsum += __shfl_down(nsum, off);
        pcnt += __shfl_down(pcnt, off);
        ncnt += __shfl_down(ncnt, off);
    }
    const int w = tid >> 6;
    if ((tid & 63) == 0) {
        red4[w][0] = psum; red4[w][1] = nsum; red4[w][2] = pcnt; red4[w][3] = ncnt;
    }
    __syncthreads();
    if (tid == 0) {
        float4 o;
        o.x = red4[0][0] + red4[1][0] + red4[2][0] + red4[3][0];
        o.y = red4[0][1] + red4[1][1] + red4[2][1] + red4[3][1];
        o.z = red4[0][2] + red4[1][2] + red4[2][2] + red4[3][2];
        o.w = red4[0][3] + red4[1][3] + red4[2][3] + red4[3][3];
        ((float4*)partials)[blockIdx.x] = o;
    }
}

// ---------------------------------------------------------------------------
// Finalize: deterministic reduce of per-block partials; n = sum(labels1 > 0)
// ---------------------------------------------------------------------------
__global__ void finalize_kernel(const int* __restrict__ L1, int N,
                                const float* __restrict__ partials, int nblocks,
                                float* __restrict__ out) {
    __shared__ float red[256][4];
    __shared__ float redn[256];
    const int tid = threadIdx.x;
    float s0 = 0.f, s1 = 0.f, s2 = 0.f, s3 = 0.f;
    for (int i = tid; i < nblocks; i += 256) {
        float4 p = ((const float4*)partials)[i];
        s0 += p.x; s1 += p.y; s2 += p.z; s3 += p.w;
    }
    int cnt = 0;
    for (int i = tid; i < N; i += 256) cnt += (L1[i] > 0) ? 1 : 0;
    red[tid][0] = s0; red[tid][1] = s1; red[tid][2] = s2; red[tid][3] = s3;
    redn[tid] = (float)cnt;
    __syncthreads();
    for (int st = 128; st; st >>= 1) {
        if (tid < st) {
            red[tid][0] += red[tid + st][0];
            red[tid][1] += red[tid + st][1];
            red[tid][2] += red[tid + st][2];
            red[tid][3] += red[tid + st][3];
            redn[tid] += redn[tid + st];
        }
        __syncthreads();
    }
    if (tid == 0) {
        float n = redn[0];
        float psum = red[0][0], nsum = red[0][1], pcnt = red[0][2], ncnt = red[0][3];
        out[0] = (psum + nsum) / n;                  // loss
        out[1] = ncnt / n;                           // avg_neg
        out[2] = rintf(100.f * pcnt / n) * 0.01f;    // avg_pos (round-half-even)
    }
}

extern "C" void kernel_launch(void* const* d_in, const int* in_sizes, int n_in,
                              void* d_out, int out_size, void* d_ws, size_t ws_size,
                              hipStream_t stream) {
    const float* x1 = (const float*)d_in[0];
    const int* l1 = (const int*)d_in[1];
    const float* x2 = (const float*)d_in[2];
    const int* l2 = (const int*)d_in[3];
    const int N = in_sizes[1];
    const int M = in_sizes[3];
    const int D = in_sizes[0] / N;
    float* out = (float*)d_out;

    // ws layout (fast path): [partials: 64 KB][Af8: N*D][Bf8: M*D]
    const size_t offPart = 0;
    const size_t offA = 65536;
    const size_t offB = offA + (size_t)N * D;
    const size_t need = offB + (size_t)M * D;
    const int nwgFast = ((N >> 7) * (M >> 7));
    const bool fast = (ws_size >= need) && ((N & 127) == 0) && ((M & 127) == 0) &&
                      ((D & 127) == 0) && (nwgFast * 16 <= 65536);

    if (fast) {
        float* partials = (float*)((char*)d_ws + offPart);
        char* Af8 = (char*)d_ws + offA;
        char* Bf8 = (char*)d_ws + offB;
        cvt_f32_to_fp8<<<2048, 256, 0, stream>>>(x1, (uint32_t*)Af8, N * D);
        cvt_f32_to_fp8<<<2048, 256, 0, stream>>>(x2, (uint32_t*)Bf8, M * D);
        sim_loss_mfma<<<nwgFast, 256, 0, stream>>>(Af8, Bf8, l1, l2, partials, N, M, D);
        finalize_kernel<<<1, 256, 0, stream>>>(l1, N, partials, nwgFast, out);
    } else {
        float* partials = (float*)d_ws;
        const int nwg = (N >> 6) * (M >> 6);
        sim_loss_f32<<<nwg, 256, 0, stream>>>(x1, x2, l1, l2, partials, N, M, D);
        finalize_kernel<<<1, 256, 0, stream>>>(l1, N, partials, nwg, out);
    }
}